// Round 2
// 6673.441 us; speedup vs baseline: 1.2682x; 1.2682x over previous
//
#include <hip/hip_runtime.h>
#include <hip/hip_bf16.h>
#include <math.h>

// ---------------------------------------------------------------------------
// Perceiver forward, MI355X. Inputs fp32, OUTPUT fp32 [B,1].
// bf16 MFMA 16x16x32 GEMMs, fp32 residual stream.
// R1: new gemm2_k for all big GEMMs: 256x128 tile, 8 waves, double-buffered
//     LDS prefetch (2-phase), XOR-swizzled LDS (kills 16-way bank conflict),
//     fast A-S erf in GEGLU epilogue.
// ws layout (232MB):
//   x    fp32 [64,512,512]    @ 0      (64MB)
//   xn   bf16 [32768,512]     @ 64MB   (32MB)  -- o aliases xn
//   q    bf16 [32768,512]     @ 96MB   (32MB)
//   kv   bf16 [32768,1024]    @ 128MB  (64MB)  -- g_half [16384,2048] aliases
//   cn   bf16 [8192,256]      @ 160MB  (4MB, cross only, inside kv region)
//   wtmp bf16 transposed wts  @ 192MB  (8MB)
//   vT   bf16 [512*64,512]    @ 200MB  (32MB)  -- V transposed per (b,h)
// ---------------------------------------------------------------------------

typedef short bf16x8 __attribute__((ext_vector_type(8)));
typedef float f32x4 __attribute__((ext_vector_type(4)));
typedef unsigned short us;

__device__ __forceinline__ float b2f(us u) {
    unsigned int i = ((unsigned int)u) << 16;
    return __builtin_bit_cast(float, i);
}
__device__ __forceinline__ us f2b(float f) {
    unsigned int x = __builtin_bit_cast(unsigned int, f);
    x += 0x7fffu + ((x >> 16) & 1u);
    return (us)(x >> 16);
}
// async global->LDS 16B DMA (wave-uniform base + lane*16 pattern)
__device__ __forceinline__ void ld16(const us* g, us* l) {
    __builtin_amdgcn_global_load_lds(
        (const __attribute__((address_space(1))) void*)g,
        (__attribute__((address_space(3))) void*)l, 16, 0, 0);
}

// exact-erf gelu via Abramowitz-Stegun 7.1.26 (|err(erf)| <= 1.5e-7),
// ~2.5x cheaper than libm erff. Invisible under bf16 output rounding.
__device__ __forceinline__ float gelu_fast(float g) {
    float z = fabsf(g) * 0.70710678118654752f;
    float t = 1.0f / (1.0f + 0.3275911f * z);
    float p = t * (0.254829592f +
              t * (-0.284496736f +
              t * (1.421413741f +
              t * (-1.453152027f +
              t * 1.061405429f))));
    float e = __expf(-z * z);
    float erfv = 1.0f - p * e;
    erfv = (g < 0.f) ? -erfv : erfv;
    return 0.5f * g * (1.0f + erfv);
}

// ---------------------------------------------------------------------------
// gemm2_k: A[M,K] bf16, Bt[N-rows,K] bf16 (pre-transposed).
// MODE 0: Out=A@B (bf16, ldout); MODE 1: X += A@B + bias (fp32);
// MODE 2: Out = (A@B+bias) * gelu(A@B2+bias2)  (GEGLU, bf16, ldout).
// 256x128 output tile (MODE2: x2 chains), BK=64, 512 threads = 8 waves
// (4Mx2N, 64x64 per wave). Double-buffered LDS + prefetch-before-compute:
//   STAGE(next) ; ds_read+MFMA(cur) ; __syncthreads  -- one barrier/K-step,
// stage latency hides under the MFMA phase.
// LDS XOR swizzle (slot ^= row&7) applied on the GLOBAL source (linear
// global_load_lds dest) and on the ds_read address -- same involution both
// sides (rule #21). Kills the 16-way row-conflict of 128B-row tiles.
// ---------------------------------------------------------------------------
template<int MODE>
__global__ __launch_bounds__(512, 2) void gemm2_k(
    const us* __restrict__ A, const us* __restrict__ Bt, const us* __restrict__ Bt2,
    const float* __restrict__ bias, const float* __restrict__ bias2,
    float* __restrict__ X, us* __restrict__ Out,
    int M, int N, int K, int ldout)
{
    constexpr int BROWS = (MODE == 2) ? 256 : 128;
    __shared__ __align__(16) us As[2][256][64];
    __shared__ __align__(16) us Bs[2][BROWS][64];

    const int tid = threadIdx.x, lane = tid & 63;
    const int l15 = lane & 15, quad = lane >> 4;
    const int wid = tid >> 6;
    const int m0 = blockIdx.y * 256, n0 = blockIdx.x * 128;
    const int wrow = (wid >> 1) * 64, wcol = (wid & 1) * 64;

    f32x4 acc[4][4];
    f32x4 acc2[4][4];
    #pragma unroll
    for (int mt = 0; mt < 4; ++mt)
        #pragma unroll
        for (int nt = 0; nt < 4; ++nt) {
            acc[mt][nt] = (f32x4){0.f, 0.f, 0.f, 0.f};
            if constexpr (MODE == 2) acc2[mt][nt] = (f32x4){0.f, 0.f, 0.f, 0.f};
        }

    auto stage = [&](int buf, int k0) {
        us* as = &As[buf][0][0];
        us* bs = &Bs[buf][0][0];
        // A tile: 256 rows x 8 chunks(16B) = 2048 chunks, 4/thread.
        // content(r, slot) = global(r, slot ^ (r&7))  [swizzled source]
        #pragma unroll
        for (int i = 0; i < 4; ++i) {
            int cidx = i * 512 + tid;
            int r = cidx >> 3;
            int c8 = ((cidx ^ r) & 7) << 3;   // (slot ^ (r&7)) * 8
            ld16(&A[(long)(m0 + r) * K + k0 + c8], as + cidx * 8);
        }
        // B tile: 128 rows = 1024 chunks, 2/thread (+ gate matrix for MODE2)
        #pragma unroll
        for (int i = 0; i < 2; ++i) {
            int cidx = i * 512 + tid;
            int r = cidx >> 3;
            int c8 = ((cidx ^ r) & 7) << 3;
            ld16(&Bt[(long)(n0 + r) * K + k0 + c8], bs + cidx * 8);
            if constexpr (MODE == 2)
                ld16(&Bt2[(long)(n0 + r) * K + k0 + c8], bs + 128 * 64 + cidx * 8);
        }
    };

    const int nsteps = K >> 6;
    stage(0, 0);
    __syncthreads();

    int cur = 0;
    for (int t = 0; t < nsteps; ++t) {
        if (t + 1 < nsteps) stage(cur ^ 1, (t + 1) << 6);   // prefetch next tile
        const us* as = &As[cur][0][0];
        const us* bs = &Bs[cur][0][0];
        #pragma unroll
        for (int kk = 0; kk < 2; ++kk) {
            const int sg = kk * 4 + quad;   // wanted 16B slot within row
            bf16x8 af[4];
            #pragma unroll
            for (int mt = 0; mt < 4; ++mt) {
                int wr = wrow + mt * 16 + l15;
                af[mt] = *(const bf16x8*)(as + wr * 64 + ((sg ^ (wr & 7)) << 3));
            }
            #pragma unroll
            for (int nt = 0; nt < 4; ++nt) {
                int br = wcol + nt * 16 + l15;
                int so = (sg ^ (br & 7)) << 3;
                bf16x8 bv = *(const bf16x8*)(bs + br * 64 + so);
                #pragma unroll
                for (int mt = 0; mt < 4; ++mt)
                    acc[mt][nt] = __builtin_amdgcn_mfma_f32_16x16x32_bf16(af[mt], bv, acc[mt][nt], 0, 0, 0);
                if constexpr (MODE == 2) {
                    bf16x8 bv2 = *(const bf16x8*)(bs + (128 + br) * 64 + so);
                    #pragma unroll
                    for (int mt = 0; mt < 4; ++mt)
                        acc2[mt][nt] = __builtin_amdgcn_mfma_f32_16x16x32_bf16(af[mt], bv2, acc2[mt][nt], 0, 0, 0);
                }
            }
        }
        __syncthreads();   // drains vmcnt(0): prefetched tile landed; cur flips
        cur ^= 1;
    }

    #pragma unroll
    for (int mt = 0; mt < 4; ++mt)
        #pragma unroll
        for (int nt = 0; nt < 4; ++nt) {
            int col = n0 + wcol + nt * 16 + l15;
            #pragma unroll
            for (int r = 0; r < 4; ++r) {
                int row = m0 + wrow + mt * 16 + quad * 4 + r;
                float v = acc[mt][nt][r];
                if constexpr (MODE == 0) {
                    Out[(long)row * ldout + col] = f2b(v);
                } else if constexpr (MODE == 1) {
                    X[(long)row * N + col] += v + bias[col];
                } else {
                    float a = v + bias[col];
                    float g = acc2[mt][nt][r] + bias2[col];
                    Out[(long)row * ldout + col] = f2b(a * gelu_fast(g));
                }
            }
        }
}

// ---------------------------------------------------------------------------
// Old GEMM kept only for cross-attn q projection (N=64 tile).
// ---------------------------------------------------------------------------
template<int BN, int MODE>
__global__ __launch_bounds__(256) void gemm_k(
    const us* __restrict__ A, const us* __restrict__ Bt, const us* __restrict__ Bt2,
    const float* __restrict__ bias, const float* __restrict__ bias2,
    float* __restrict__ X, us* __restrict__ Out,
    int M, int N, int K, int ldout)
{
    __shared__ __align__(16) us As[128][64];
    __shared__ __align__(16) us Bs[(MODE == 2 ? 2 : 1) * BN][64];

    const int tid = threadIdx.x, wave = tid >> 6, lane = tid & 63;
    const int l15 = lane & 15, quad = lane >> 4;
    const int m0 = blockIdx.y * 128, n0 = blockIdx.x * BN;

    constexpr int MT = (BN == 128) ? 4 : 2;
    constexpr int NT = 4;
    constexpr int BV = BN / 32;
    const int wrow = (BN == 128) ? (wave >> 1) * 64 : wave * 32;
    const int wcol = (BN == 128) ? (wave & 1) * 64 : 0;

    f32x4 acc[MT][NT], acc2[MT][NT];
    #pragma unroll
    for (int mt = 0; mt < MT; ++mt)
        #pragma unroll
        for (int nt = 0; nt < NT; ++nt) {
            acc[mt][nt] = (f32x4){0.f, 0.f, 0.f, 0.f};
            acc2[mt][nt] = (f32x4){0.f, 0.f, 0.f, 0.f};
        }

    for (int k0 = 0; k0 < K; k0 += 64) {
        __syncthreads();
        #pragma unroll
        for (int i = 0; i < 4; ++i) {
            int cidx = i * 256 + tid;
            int r = cidx >> 3, c8 = (cidx & 7) * 8;
            ld16(&A[(long)(m0 + r) * K + k0 + c8], &As[0][0] + cidx * 8);
        }
        #pragma unroll
        for (int i = 0; i < BV; ++i) {
            int cidx = i * 256 + tid;
            int r = cidx >> 3, c8 = (cidx & 7) * 8;
            ld16(&Bt[(long)(n0 + r) * K + k0 + c8], &Bs[0][0] + cidx * 8);
            if (MODE == 2)
                ld16(&Bt2[(long)(n0 + r) * K + k0 + c8], &Bs[BN][0] + cidx * 8);
        }
        __syncthreads();
        #pragma unroll
        for (int kk = 0; kk < 2; ++kk) {
            bf16x8 af[MT];
            #pragma unroll
            for (int mt = 0; mt < MT; ++mt)
                af[mt] = *(const bf16x8*)&As[wrow + mt * 16 + l15][kk * 32 + quad * 8];
            #pragma unroll
            for (int nt = 0; nt < NT; ++nt) {
                bf16x8 bv = *(const bf16x8*)&Bs[wcol + nt * 16 + l15][kk * 32 + quad * 8];
                #pragma unroll
                for (int mt = 0; mt < MT; ++mt)
                    acc[mt][nt] = __builtin_amdgcn_mfma_f32_16x16x32_bf16(af[mt], bv, acc[mt][nt], 0, 0, 0);
                if (MODE == 2) {
                    bf16x8 bv2 = *(const bf16x8*)&Bs[BN + wcol + nt * 16 + l15][kk * 32 + quad * 8];
                    #pragma unroll
                    for (int mt = 0; mt < MT; ++mt)
                        acc2[mt][nt] = __builtin_amdgcn_mfma_f32_16x16x32_bf16(af[mt], bv2, acc2[mt][nt], 0, 0, 0);
                }
            }
        }
    }

    #pragma unroll
    for (int mt = 0; mt < MT; ++mt)
        #pragma unroll
        for (int nt = 0; nt < NT; ++nt)
            #pragma unroll
            for (int r = 0; r < 4; ++r) {
                int row = m0 + wrow + mt * 16 + quad * 4 + r;
                int col = n0 + wcol + nt * 16 + l15;
                float v = acc[mt][nt][r];
                if (MODE == 0) {
                    Out[(long)row * ldout + col] = f2b(v);
                } else if (MODE == 1) {
                    X[(long)row * N + col] += v + bias[col];
                } else {
                    float a = v + bias[col];
                    float g = acc2[mt][nt][r] + bias2[col];
                    float ge = gelu_fast(g);
                    Out[(long)row * ldout + col] = f2b(a * ge);
                }
            }
}

// ---------------------------------------------------------------------------
// Flash self-attention. q/o [32768,512] (8 heads x 64), kv [32768,1024]
// (K in cols 0..511 by head), vT [(b*8+h)*64+d][512] pre-transposed V.
// ---------------------------------------------------------------------------
__global__ __launch_bounds__(256, 2) void attn_self_k(
    const us* __restrict__ q, const us* __restrict__ kv,
    const us* __restrict__ vT, us* __restrict__ o)
{
    __shared__ __align__(16) us Ks[64][64];
    __shared__ __align__(16) us Vs[64][64];
    __shared__ __align__(16) us Ps[4][64][72];

    const int tid = threadIdx.x, wave = tid >> 6, lane = tid & 63;
    const int l15 = lane & 15, quad = lane >> 4;
    const int qt = blockIdx.x, h = blockIdx.y, b = blockIdx.z;
    const long qrow0 = (long)b * 512 + qt * 256 + wave * 64;
    const float scale = 0.125f;

    bf16x8 Qf[4][2];
    #pragma unroll
    for (int ntq = 0; ntq < 4; ++ntq)
        #pragma unroll
        for (int kk = 0; kk < 2; ++kk)
            Qf[ntq][kk] = *(const bf16x8*)&q[(qrow0 + ntq * 16 + l15) * 512 + h * 64 + kk * 32 + quad * 8];

    f32x4 O[4][4];
    #pragma unroll
    for (int mt = 0; mt < 4; ++mt)
        #pragma unroll
        for (int nt = 0; nt < 4; ++nt) O[mt][nt] = (f32x4){0.f, 0.f, 0.f, 0.f};
    float m_[4] = {-1e30f, -1e30f, -1e30f, -1e30f};
    float l_[4] = {0.f, 0.f, 0.f, 0.f};

    for (int jt = 0; jt < 8; ++jt) {
        __syncthreads();
        #pragma unroll
        for (int i = 0; i < 2; ++i) {
            int cidx = i * 256 + tid;
            int r = cidx >> 3, c8 = (cidx & 7) * 8;
            ld16(&kv[((long)b * 512 + jt * 64 + r) * 1024 + h * 64 + c8], &Ks[0][0] + cidx * 8);
            ld16(&vT[((long)(b * 8 + h) * 64 + r) * 512 + jt * 64 + c8], &Vs[0][0] + cidx * 8);
        }
        __syncthreads();

        f32x4 St[4][4];
        #pragma unroll
        for (int mt = 0; mt < 4; ++mt)
            #pragma unroll
            for (int nt = 0; nt < 4; ++nt) St[mt][nt] = (f32x4){0.f, 0.f, 0.f, 0.f};
        #pragma unroll
        for (int kk = 0; kk < 2; ++kk) {
            bf16x8 aK[4];
            #pragma unroll
            for (int mtj = 0; mtj < 4; ++mtj)
                aK[mtj] = *(const bf16x8*)&Ks[mtj * 16 + l15][kk * 32 + quad * 8];
            #pragma unroll
            for (int ntq = 0; ntq < 4; ++ntq)
                #pragma unroll
                for (int mtj = 0; mtj < 4; ++mtj)
                    St[mtj][ntq] = __builtin_amdgcn_mfma_f32_16x16x32_bf16(aK[mtj], Qf[ntq][kk], St[mtj][ntq], 0, 0, 0);
        }

        float al[4];
        #pragma unroll
        for (int ntq = 0; ntq < 4; ++ntq) {
            float cm = -1e30f;
            #pragma unroll
            for (int mtj = 0; mtj < 4; ++mtj)
                #pragma unroll
                for (int r = 0; r < 4; ++r) cm = fmaxf(cm, St[mtj][ntq][r]);
            cm = fmaxf(cm, __shfl_xor(cm, 16));
            cm = fmaxf(cm, __shfl_xor(cm, 32));
            float M = fmaxf(m_[ntq], cm);
            al[ntq] = __expf((m_[ntq] - M) * scale);
            m_[ntq] = M;
            float psum = 0.f;
            #pragma unroll
            for (int mtj = 0; mtj < 4; ++mtj)
                #pragma unroll
                for (int r = 0; r < 4; ++r) {
                    float p = __expf((St[mtj][ntq][r] - M) * scale);
                    psum += p; St[mtj][ntq][r] = p;
                }
            l_[ntq] = l_[ntq] * al[ntq] + psum;
        }
        #pragma unroll
        for (int mto = 0; mto < 4; ++mto)
            #pragma unroll
            for (int r = 0; r < 4; ++r) {
                float a = __shfl(al[mto], quad * 4 + r);
                #pragma unroll
                for (int ntd = 0; ntd < 4; ++ntd) O[mto][ntd][r] *= a;
            }
        #pragma unroll
        for (int ntq = 0; ntq < 4; ++ntq)
            #pragma unroll
            for (int mtj = 0; mtj < 4; ++mtj) {
                union { us u[4]; uint2 v; } pk;
                #pragma unroll
                for (int r = 0; r < 4; ++r) pk.u[r] = f2b(St[mtj][ntq][r]);
                *(uint2*)&Ps[wave][ntq * 16 + l15][mtj * 16 + quad * 4] = pk.v;
            }
        #pragma unroll
        for (int kk = 0; kk < 2; ++kk) {
            bf16x8 aP[4];
            #pragma unroll
            for (int mto = 0; mto < 4; ++mto)
                aP[mto] = *(const bf16x8*)&Ps[wave][mto * 16 + l15][kk * 32 + quad * 8];
            #pragma unroll
            for (int ntd = 0; ntd < 4; ++ntd) {
                bf16x8 bV = *(const bf16x8*)&Vs[ntd * 16 + l15][kk * 32 + quad * 8];
                #pragma unroll
                for (int mto = 0; mto < 4; ++mto)
                    O[mto][ntd] = __builtin_amdgcn_mfma_f32_16x16x32_bf16(aP[mto], bV, O[mto][ntd], 0, 0, 0);
            }
        }
    }

    float li[4];
    #pragma unroll
    for (int ntq = 0; ntq < 4; ++ntq) {
        float s = l_[ntq];
        s += __shfl_xor(s, 16);
        s += __shfl_xor(s, 32);
        li[ntq] = 1.f / s;
    }
    #pragma unroll
    for (int mto = 0; mto < 4; ++mto)
        #pragma unroll
        for (int r = 0; r < 4; ++r) {
            float inv = __shfl(li[mto], quad * 4 + r);
            #pragma unroll
            for (int ntd = 0; ntd < 4; ++ntd)
                o[(qrow0 + mto * 16 + quad * 4 + r) * 512 + h * 64 + ntd * 16 + l15] = f2b(O[mto][ntd][r] * inv);
        }
}

// V transpose per (b,h): kv[b*512+j][512 + h*64 + d] -> vT[(b*8+h)*64 + d][j]
__global__ __launch_bounds__(256) void transv_k(
    const us* __restrict__ kv, us* __restrict__ vT)
{
    __shared__ us tile[32][33];
    const int bh = blockIdx.z, b = bh >> 3, h = bh & 7;
    const int j0 = blockIdx.y * 32, d0 = blockIdx.x * 32;
    const int c = threadIdx.x & 31, r8 = threadIdx.x >> 5;
    #pragma unroll
    for (int i = 0; i < 4; ++i) {
        int r = r8 + i * 8;
        tile[r][c] = kv[((long)b * 512 + j0 + r) * 1024 + 512 + h * 64 + d0 + c];
    }
    __syncthreads();
    #pragma unroll
    for (int i = 0; i < 4; ++i) {
        int r = r8 + i * 8;
        vT[((long)bh * 64 + d0 + r) * 512 + j0 + c] = tile[c][r];
    }
}

// ---------------------------------------------------------------------------
// Cross attention (J=128, H=1) — known correct, small cost.
// ---------------------------------------------------------------------------
template<int J>
__global__ __launch_bounds__(256) void attn_k(
    const us* __restrict__ q, const us* __restrict__ kv,
    us* __restrict__ o, int H)
{
    __shared__ __align__(16) us Qs[64][72];
    __shared__ __align__(16) us Ksh[64][72];
    __shared__ __align__(16) us Vt[64][72];
    __shared__ __align__(16) us Ps[4][16][72];

    const int tid = threadIdx.x, wave = tid >> 6, lane = tid & 63;
    const int l15 = lane & 15, quad = lane >> 4;
    const int b = blockIdx.z, h = blockIdx.y, qt = blockIdx.x;
    const int qstride = H * 64, kvstride = H * 128;
    const long qbase = (long)b * 512 + qt * 64;
    constexpr int JT = J / 64;

    #pragma unroll
    for (int i = 0; i < 2; ++i) {
        int v = tid + i * 256; int r = v >> 3, c8 = (v & 7) * 8;
        *(uint4*)&Qs[r][c8] = *(const uint4*)&q[(qbase + r) * qstride + h * 64 + c8];
    }

    f32x4 S[JT * 4];
    #pragma unroll
    for (int t = 0; t < JT * 4; ++t) S[t] = (f32x4){0.f, 0.f, 0.f, 0.f};
    const int wrow = wave * 16;

    #pragma unroll
    for (int jt = 0; jt < JT; ++jt) {
        __syncthreads();
        #pragma unroll
        for (int i = 0; i < 2; ++i) {
            int v = tid + i * 256; int r = v >> 3, c8 = (v & 7) * 8;
            *(uint4*)&Ksh[r][c8] = *(const uint4*)&kv[((long)b * J + jt * 64 + r) * kvstride + h * 64 + c8];
        }
        __syncthreads();
        #pragma unroll
        for (int kk = 0; kk < 2; ++kk) {
            bf16x8 af = *(const bf16x8*)&Qs[wrow + l15][kk * 32 + quad * 8];
            #pragma unroll
            for (int nt = 0; nt < 4; ++nt) {
                bf16x8 bv = *(const bf16x8*)&Ksh[nt * 16 + l15][kk * 32 + quad * 8];
                S[jt * 4 + nt] = __builtin_amdgcn_mfma_f32_16x16x32_bf16(af, bv, S[jt * 4 + nt], 0, 0, 0);
            }
        }
    }

    const float scale = 0.125f;
    float mx[4] = {-3.4e38f, -3.4e38f, -3.4e38f, -3.4e38f};
    #pragma unroll
    for (int t = 0; t < JT * 4; ++t)
        #pragma unroll
        for (int r = 0; r < 4; ++r) mx[r] = fmaxf(mx[r], S[t][r]);
    #pragma unroll
    for (int off = 1; off < 16; off <<= 1)
        #pragma unroll
        for (int r = 0; r < 4; ++r) mx[r] = fmaxf(mx[r], __shfl_xor(mx[r], off));
    float l[4] = {0.f, 0.f, 0.f, 0.f};
    #pragma unroll
    for (int t = 0; t < JT * 4; ++t)
        #pragma unroll
        for (int r = 0; r < 4; ++r) {
            float p = expf((S[t][r] - mx[r]) * scale);
            S[t][r] = p; l[r] += p;
        }
    #pragma unroll
    for (int off = 1; off < 16; off <<= 1)
        #pragma unroll
        for (int r = 0; r < 4; ++r) l[r] += __shfl_xor(l[r], off);
    float linv[4];
    #pragma unroll
    for (int r = 0; r < 4; ++r) linv[r] = 1.f / l[r];

    f32x4 O[4];
    #pragma unroll
    for (int nt = 0; nt < 4; ++nt) O[nt] = (f32x4){0.f, 0.f, 0.f, 0.f};

    #pragma unroll
    for (int jt = 0; jt < JT; ++jt) {
        __syncthreads();
        #pragma unroll
        for (int nt = 0; nt < 4; ++nt)
            #pragma unroll
            for (int r = 0; r < 4; ++r)
                Ps[wave][quad * 4 + r][nt * 16 + l15] = f2b(S[jt * 4 + nt][r]);
        #pragma unroll
        for (int i = 0; i < 2; ++i) {
            int v = tid + i * 256; int j = v >> 3, c8 = (v & 7) * 8;
            alignas(16) us tmp[8];
            *(uint4*)tmp = *(const uint4*)&kv[((long)b * J + jt * 64 + j) * kvstride + (long)H * 64 + h * 64 + c8];
            #pragma unroll
            for (int e = 0; e < 8; ++e) Vt[c8 + e][j] = tmp[e];
        }
        __syncthreads();
        #pragma unroll
        for (int kk = 0; kk < 2; ++kk) {
            bf16x8 af = *(const bf16x8*)&Ps[wave][l15][kk * 32 + quad * 8];
            #pragma unroll
            for (int nt = 0; nt < 4; ++nt) {
                bf16x8 bv = *(const bf16x8*)&Vt[nt * 16 + l15][kk * 32 + quad * 8];
                O[nt] = __builtin_amdgcn_mfma_f32_16x16x32_bf16(af, bv, O[nt], 0, 0, 0);
            }
        }
    }

    #pragma unroll
    for (int nt = 0; nt < 4; ++nt)
        #pragma unroll
        for (int r = 0; r < 4; ++r) {
            long row = qbase + wrow + quad * 4 + r;
            int col = h * 64 + nt * 16 + l15;
            o[row * qstride + col] = f2b(O[nt][r] * linv[r]);
        }
}

// ---------------------------------------------------------------------------
__global__ __launch_bounds__(256) void ln512_k(
    const float* __restrict__ Xin, const float* __restrict__ g,
    const float* __restrict__ b, us* __restrict__ Out)
{
    const int wave = threadIdx.x >> 6, lane = threadIdx.x & 63;
    const long row = (long)blockIdx.x * 4 + wave;
    const float* xr = Xin + row * 512;
    float4 v0 = *(const float4*)(xr + lane * 4);
    float4 v1 = *(const float4*)(xr + 256 + lane * 4);
    float va[8] = {v0.x, v0.y, v0.z, v0.w, v1.x, v1.y, v1.z, v1.w};
    float s = 0.f, qq = 0.f;
    #pragma unroll
    for (int i = 0; i < 8; ++i) { s += va[i]; qq += va[i] * va[i]; }
    #pragma unroll
    for (int off = 1; off < 64; off <<= 1) { s += __shfl_xor(s, off); qq += __shfl_xor(qq, off); }
    float mean = s * (1.f / 512.f);
    float var = qq * (1.f / 512.f) - mean * mean;
    float inv = rsqrtf(var + 1e-5f);
    alignas(8) us ov[8];
    #pragma unroll
    for (int i = 0; i < 8; ++i) {
        int c = (i < 4) ? lane * 4 + i : 256 + lane * 4 + (i - 4);
        ov[i] = f2b((va[i] - mean) * inv * g[c] + b[c]);
    }
    *(uint2*)(Out + row * 512 + lane * 4) = *(uint2*)&ov[0];
    *(uint2*)(Out + row * 512 + 256 + lane * 4) = *(uint2*)&ov[4];
}

__global__ __launch_bounds__(256) void ln256_k(
    const float* __restrict__ Xin, const float* __restrict__ g,
    const float* __restrict__ b, us* __restrict__ Out)
{
    const int wave = threadIdx.x >> 6, lane = threadIdx.x & 63;
    const long row = (long)blockIdx.x * 4 + wave;
    const float* xr = Xin + row * 256;
    float4 v = *(const float4*)(xr + lane * 4);
    float va[4] = {v.x, v.y, v.z, v.w};
    float s = 0.f, qq = 0.f;
    #pragma unroll
    for (int i = 0; i < 4; ++i) { s += va[i]; qq += va[i] * va[i]; }
    #pragma unroll
    for (int off = 1; off < 64; off <<= 1) { s += __shfl_xor(s, off); qq += __shfl_xor(qq, off); }
    float mean = s * (1.f / 256.f);
    float var = qq * (1.f / 256.f) - mean * mean;
    float inv = rsqrtf(var + 1e-5f);
    alignas(8) us ov[4];
    #pragma unroll
    for (int i = 0; i < 4; ++i)
        ov[i] = f2b((va[i] - mean) * inv * g[lane * 4 + i] + b[lane * 4 + i]);
    *(uint2*)(Out + row * 256 + lane * 4) = *(uint2*)&ov[0];
}

// ---------------------------------------------------------------------------
struct T5 {
    const float* s[5];
    us* d[5];
    int R[5];
    int C[5];
};

__global__ __launch_bounds__(256) void trans5_k(T5 t)
{
    __shared__ float tile[32][33];
    const int seg = blockIdx.z;
    const int R = t.R[seg], C = t.C[seg];
    const int r0 = blockIdx.y * 32, c0 = blockIdx.x * 32;
    if (r0 >= R || c0 >= C) return;
    const float* __restrict__ src = t.s[seg];
    us* __restrict__ dst = t.d[seg];
    const int c = threadIdx.x & 31, r8 = threadIdx.x >> 5;
    #pragma unroll
    for (int i = 0; i < 4; ++i) {
        int r = r8 + i * 8;
        tile[r][c] = src[(long)(r0 + r) * C + c0 + c];
    }
    __syncthreads();
    #pragma unroll
    for (int i = 0; i < 4; ++i) {
        int r = r8 + i * 8;
        dst[(long)(c0 + r) * R + r0 + c] = f2b(tile[c][r]);
    }
}

__global__ __launch_bounds__(256) void initx_k(
    const float* __restrict__ lat, float* __restrict__ x)
{
    long v = ((long)blockIdx.x * 256 + threadIdx.x) * 4;
    *(float4*)&x[v] = *(const float4*)&lat[v & 262143];
}

__global__ __launch_bounds__(256) void head_k(
    const float* __restrict__ x, const float* __restrict__ hg,
    const float* __restrict__ hb, const float* __restrict__ hw,
    const float* __restrict__ hbias, float* __restrict__ out)
{
    const int b = blockIdx.x, t = threadIdx.x;
    const int wave = t >> 6, lane = t & 63;
    const float* xb = x + (long)b * 512 * 512;
    float s0 = 0.f, s1 = 0.f;
    for (int i = 0; i < 512; ++i) {
        s0 += xb[(long)i * 512 + t];
        s1 += xb[(long)i * 512 + t + 256];
    }
    float p0 = s0 * (1.f / 512.f), p1 = s1 * (1.f / 512.f);
    float sum = p0 + p1, sq = p0 * p0 + p1 * p1;
    #pragma unroll
    for (int off = 1; off < 64; off <<= 1) { sum += __shfl_xor(sum, off); sq += __shfl_xor(sq, off); }
    __shared__ float rs[4], rq[4];
    if (lane == 0) { rs[wave] = sum; rq[wave] = sq; }
    __syncthreads();
    float tots = rs[0] + rs[1] + rs[2] + rs[3];
    float totq = rq[0] + rq[1] + rq[2] + rq[3];
    float mean = tots * (1.f / 512.f);
    float var = totq * (1.f / 512.f) - mean * mean;
    float inv = rsqrtf(var + 1e-5f);
    float y0 = (p0 - mean) * inv * hg[t] + hb[t];
    float y1 = (p1 - mean) * inv * hg[t + 256] + hb[t + 256];
    float d = y0 * hw[t] + y1 * hw[t + 256];
    #pragma unroll
    for (int off = 1; off < 64; off <<= 1) d += __shfl_xor(d, off);
    __syncthreads();
    if (lane == 0) rs[wave] = d;
    __syncthreads();
    if (t == 0) out[b] = rs[0] + rs[1] + rs[2] + rs[3] + hbias[0];
}

// ---------------------------------------------------------------------------
extern "C" void kernel_launch(void* const* d_in, const int* in_sizes, int n_in,
                              void* d_out, int out_size, void* d_ws, size_t ws_size,
                              hipStream_t stream)
{
    const float* data   = (const float*)d_in[0];
    const float* lat    = (const float*)d_in[1];
    const float* ca_ng  = (const float*)d_in[2];
    const float* ca_nb  = (const float*)d_in[3];
    const float* ca_cg  = (const float*)d_in[4];
    const float* ca_cb  = (const float*)d_in[5];
    const float* ca_wq  = (const float*)d_in[6];
    const float* ca_wkv = (const float*)d_in[7];
    const float* ca_wo  = (const float*)d_in[8];
    const float* ca_bo  = (const float*)d_in[9];
    const float* cf_ng  = (const float*)d_in[10];
    const float* cf_nb  = (const float*)d_in[11];
    const float* cf_w1  = (const float*)d_in[12];
    const float* cf_b1  = (const float*)d_in[13];
    const float* cf_w2  = (const float*)d_in[14];
    const float* cf_b2  = (const float*)d_in[15];
    const float* sa_ng  = (const float*)d_in[16];
    const float* sa_nb  = (const float*)d_in[17];
    const float* sa_wq  = (const float*)d_in[18];
    const float* sa_wkv = (const float*)d_in[19];
    const float* sa_wo  = (const float*)d_in[20];
    const float* sa_bo  = (const float*)d_in[21];
    const float* sf_ng  = (const float*)d_in[22];
    const float* sf_nb  = (const float*)d_in[23];
    const float* sf_w1  = (const float*)d_in[24];
    const float* sf_b1  = (const float*)d_in[25];
    const float* sf_w2  = (const float*)d_in[26];
    const float* sf_b2  = (const float*)d_in[27];
    const float* head_g = (const float*)d_in[28];
    const float* head_b = (const float*)d_in[29];
    const float* head_w = (const float*)d_in[30];
    const float* head_bias = (const float*)d_in[31];
    float* out = (float*)d_out;

    char* ws = (char*)d_ws;
    const size_t MB = 1048576;
    float* x  = (float*)ws;                 // 0..64MB
    us* xn    = (us*)(ws + 64 * MB);        // 64..96MB (o aliases)
    us* ob    = xn;
    us* qb    = (us*)(ws + 96 * MB);        // 96..128MB
    us* kvb   = (us*)(ws + 128 * MB);       // 128..192MB (g aliases)
    us* gb    = kvb;
    us* cn    = (us*)(ws + 160 * MB);       // cross only
    us* wt    = (us*)(ws + 192 * MB);       // 192..200MB
    us* vTb   = (us*)(ws + 200 * MB);       // 200..232MB

    const dim3 B256(256);
    const dim3 B512(512);
    const dim3 TGRID(128, 64, 5);

    initx_k<<<16384, B256, 0, stream>>>(lat, x);

    for (int i = 0; i < 4; ++i) {
        us* wqT  = wt;                       // [64][512]
        us* wkvT = wt + 32768;               // [128][256]
        us* woT  = wt + 65536;               // [512][64]
        us* w1T  = wt + 98304;               // [4096][512]
        us* w2T  = wt + 2195456;             // [512][2048]
        {
            T5 t;
            t.s[0] = ca_wq  + i * 32768;   t.d[0] = wqT;  t.R[0] = 512;  t.C[0] = 64;
            t.s[1] = ca_wkv + i * 32768;   t.d[1] = wkvT; t.R[1] = 256;  t.C[1] = 128;
            t.s[2] = ca_wo  + i * 32768;   t.d[2] = woT;  t.R[2] = 64;   t.C[2] = 512;
            t.s[3] = cf_w1  + i * 2097152; t.d[3] = w1T;  t.R[3] = 512;  t.C[3] = 4096;
            t.s[4] = cf_w2  + i * 1048576; t.d[4] = w2T;  t.R[4] = 2048; t.C[4] = 512;
            trans5_k<<<TGRID, B256, 0, stream>>>(t);
        }
        // ---- cross attention ----
        ln256_k<<<2048, B256, 0, stream>>>(data, ca_cg + i * 256, ca_cb + i * 256, cn);
        ln512_k<<<8192, B256, 0, stream>>>(x, ca_ng + i * 512, ca_nb + i * 512, xn);
        gemm_k<64, 0><<<dim3(1, 256), B256, 0, stream>>>(
            xn, wqT, nullptr, nullptr, nullptr, nullptr, qb, 32768, 64, 512, 64);
        gemm2_k<0><<<dim3(1, 32), B512, 0, stream>>>(
            cn, wkvT, nullptr, nullptr, nullptr, nullptr, kvb, 8192, 128, 256, 128);
        attn_k<128><<<dim3(8, 1, 64), B256, 0, stream>>>(qb, kvb, ob, 1);
        gemm2_k<1><<<dim3(4, 128), B512, 0, stream>>>(
            ob, woT, nullptr, ca_bo + i * 512, nullptr, x, nullptr, 32768, 512, 64, 512);
        // ---- cross FF (GEGLU) ----
        ln512_k<<<8192, B256, 0, stream>>>(x, cf_ng + i * 512, cf_nb + i * 512, xn);
        for (int hh = 0; hh < 2; ++hh) {
            const us* ah = xn + (long)hh * 16384 * 512;
            float* xh = x + (long)hh * 16384 * 512;
            gemm2_k<2><<<dim3(16, 64), B512, 0, stream>>>(
                ah, w1T, w1T + 1048576, cf_b1 + i * 4096, cf_b1 + i * 4096 + 2048,
                nullptr, gb, 16384, 2048, 512, 2048);
            gemm2_k<1><<<dim3(4, 64), B512, 0, stream>>>(
                gb, w2T, nullptr, cf_b2 + i * 512, nullptr, xh, nullptr, 16384, 512, 2048, 512);
        }
        // ---- latent self-attn blocks ----
        for (int j = 0; j < 2; ++j) {
            int d2 = i * 2 + j;
            us* sqT  = wt;                   // [512][512]
            us* skvT = wt + 262144;          // [1024][512]
            us* soT  = wt + 786432;          // [512][512]
            us* sw1T = wt + 1048576;         // [4096][512]
            us* sw2T = wt + 3145728;         // [512][2048]
            {
                T5 t;
                t.s[0] = sa_wq  + (long)d2 * 262144;  t.d[0] = sqT;  t.R[0] = 512;  t.C[0] = 512;
                t.s[1] = sa_wkv + (long)d2 * 524288;  t.d[1] = skvT; t.R[1] = 512;  t.C[1] = 1024;
                t.s[2] = sa_wo  + (long)d2 * 262144;  t.d[2] = soT;  t.R[2] = 512;  t.C[2] = 512;
                t.s[3] = sf_w1  + (long)d2 * 2097152; t.d[3] = sw1T; t.R[3] = 512;  t.C[3] = 4096;
                t.s[4] = sf_w2  + (long)d2 * 1048576; t.d[4] = sw2T; t.R[4] = 2048; t.C[4] = 512;
                trans5_k<<<TGRID, B256, 0, stream>>>(t);
            }
            ln512_k<<<8192, B256, 0, stream>>>(x, sa_ng + d2 * 512, sa_nb + d2 * 512, xn);
            gemm2_k<0><<<dim3(4, 128), B512, 0, stream>>>(
                xn, sqT, nullptr, nullptr, nullptr, nullptr, qb, 32768, 512, 512, 512);
            gemm2_k<0><<<dim3(8, 128), B512, 0, stream>>>(
                xn, skvT, nullptr, nullptr, nullptr, nullptr, kvb, 32768, 1024, 512, 1024);
            transv_k<<<dim3(2, 16, 512), B256, 0, stream>>>(kvb, vTb);
            attn_self_k<<<dim3(2, 8, 64), B256, 0, stream>>>(qb, kvb, vTb, ob);
            gemm2_k<1><<<dim3(4, 128), B512, 0, stream>>>(
                ob, soT, nullptr, sa_bo + d2 * 512, nullptr, x, nullptr, 32768, 512, 512, 512);
            ln512_k<<<8192, B256, 0, stream>>>(x, sf_ng + d2 * 512, sf_nb + d2 * 512, xn);
            for (int hh = 0; hh < 2; ++hh) {
                const us* ah = xn + (long)hh * 16384 * 512;
                float* xh = x + (long)hh * 16384 * 512;
                gemm2_k<2><<<dim3(16, 64), B512, 0, stream>>>(
                    ah, sw1T, sw1T + 1048576, sf_b1 + d2 * 4096, sf_b1 + d2 * 4096 + 2048,
                    nullptr, gb, 16384, 2048, 512, 2048);
                gemm2_k<1><<<dim3(4, 64), B512, 0, stream>>>(
                    gb, sw2T, nullptr, sf_b2 + d2 * 512, nullptr, xh, nullptr, 16384, 512, 2048, 512);
            }
        }
    }
    head_k<<<64, B256, 0, stream>>>(x, head_g, head_b, head_w, head_bias, out);
}